// Round 12
// baseline (8242.567 us; speedup 1.0000x reference)
//
#include <hip/hip_runtime.h>
#include <hip/hip_bf16.h>

// ---------------------------------------------------------------------------
// 2-layer LSTM, B=32, T=512, H=1024, fp32 in/out.
// Round 12 (base = r11, 7.87ms passed, absmax 0.0546875):
//   ONE change: hierarchical arrival barrier (r6-proven protocol).
//   r11's symmetric arrival poll = 256 wgs x 256 lines = 65K MALL
//   line-requests per round (256-way same-line fan-out) - a control-plane
//   broadcast storm, masked in r6 by the (since-fixed) h-broadcast.
//   Now: wg0's tid<256 poll the 256 arrival flags (256 req/round, one wg),
//   tid0 stores `go`; all other wgs poll `go` with ONE thread + s_sleep,
//   then __syncthreads. ~500 req/round total. Ordering transitively correct
//   through MALL (drain -> flag -> wg0 -> go -> consumer UC reads).
//   Everything else byte-identical to r11 (multicast staging, packed h,
//   done-flags, xterms overlap, 256wg x 512thr).
// ---------------------------------------------------------------------------

constexpr int Hh = 1024;
constexpr int Bb = 32;
constexpr int Tt = 512;
constexpr int NWG = 256;
constexpr int PLE  = 32 * 1024;        // elems per staged plane [32][1024]
constexpr int ST4E = 4 * PLE;          // 4 planes per staged slot

typedef float f32x4 __attribute__((ext_vector_type(4)));
typedef int   i32x4 __attribute__((ext_vector_type(4)));

__device__ inline void mfma_bf16(f32x4& acc, i32x4 a, i32x4 b) {
    // s_nop 2 guards compiler-inserted VALU writes before the MFMA reads.
    asm("s_nop 2\n\tv_mfma_f32_16x16x32_bf16 %0, %1, %2, %0"
        : "+v"(acc) : "v"(a), "v"(b));
}

// Coherent (cross-XCD) 16B load: two relaxed agent 8B atomic loads.
__device__ inline i32x4 aload_x4(const void* p) {
    const unsigned long long* q = (const unsigned long long*)p;
    unsigned long long a = __hip_atomic_load(q,     __ATOMIC_RELAXED, __HIP_MEMORY_SCOPE_AGENT);
    unsigned long long b = __hip_atomic_load(q + 1, __ATOMIC_RELAXED, __HIP_MEMORY_SCOPE_AGENT);
    i32x4 r;
    r[0] = (int)(unsigned)a; r[1] = (int)(a >> 32);
    r[2] = (int)(unsigned)b; r[3] = (int)(b >> 32);
    return r;
}
__device__ inline i32x4 pload_x4(const unsigned short* p) {  // plain cached
    return *(const i32x4*)p;
}
__device__ inline void astore_u32(unsigned int* p, unsigned v) {
    __hip_atomic_store(p, v, __ATOMIC_RELAXED, __HIP_MEMORY_SCOPE_AGENT);
}
__device__ inline unsigned aload_u32(const unsigned int* p) {
    return __hip_atomic_load(p, __ATOMIC_RELAXED, __HIP_MEMORY_SCOPE_AGENT);
}

__device__ inline unsigned short f2bf(float f) {
    unsigned u = __float_as_uint(f);
    u += 0x7fffu + ((u >> 16) & 1u);   // round-to-nearest-even
    return (unsigned short)(u >> 16);
}
__device__ inline float bf2f(unsigned short s) {
    return __uint_as_float((unsigned)s << 16);
}

__device__ inline float sigm(float x)  { return 1.f / (1.f + __expf(-x)); }
__device__ inline float tanh_f(float x){ return 1.f - 2.f / (__expf(2.f * x) + 1.f); }

// x [32][512][1024] f32 -> xT hi/lo [513][32][1024] bf16 (slot 512 zeroed)
__global__ __launch_bounds__(256) void k_xT(const float* __restrict__ x,
                                            unsigned short* __restrict__ xh,
                                            unsigned short* __restrict__ xl,
                                            int use_lo) {
    int bid = blockIdx.x;               // 0..16415
    int t = bid >> 5, b = bid & 31;
    size_t o = ((size_t)t * Bb + b) * Hh;
    if (t == Tt) {
        ushort4 z = {0, 0, 0, 0};
        ((ushort4*)(xh + o))[threadIdx.x] = z;
        if (use_lo) ((ushort4*)(xl + o))[threadIdx.x] = z;
        return;
    }
    const float4* src = (const float4*)(x + ((size_t)b * Tt + t) * Hh);
    float4 v = src[threadIdx.x];
    ushort4 hi;
    hi.x = f2bf(v.x); hi.y = f2bf(v.y); hi.z = f2bf(v.z); hi.w = f2bf(v.w);
    ((ushort4*)(xh + o))[threadIdx.x] = hi;
    if (use_lo) {
        ushort4 lo;
        lo.x = f2bf(v.x - bf2f(hi.x));
        lo.y = f2bf(v.y - bf2f(hi.y));
        lo.z = f2bf(v.z - bf2f(hi.z));
        lo.w = f2bf(v.w - bf2f(hi.w));
        ((ushort4*)(xl + o))[threadIdx.x] = lo;
    }
}

// W[mat] [1024][4096] f32 -> wh[mat][wg][col(16)][k(1024)] bf16 (4 mats),
// lo planes only for mats 0,2 (w_ih0, w_ih1) packed at lo-slot mat>>1.
__global__ __launch_bounds__(256) void k_warr(const float* __restrict__ w0,
                                              const float* __restrict__ w1,
                                              const float* __restrict__ w2,
                                              const float* __restrict__ w3,
                                              unsigned short* __restrict__ wh,
                                              unsigned short* __restrict__ wl,
                                              int use_lo) {
    int bid = blockIdx.x;               // 0..1023
    int mat = bid >> 8, wg = bid & 255;
    const float* W = (mat == 0) ? w0 : (mat == 1) ? w1 : (mat == 2) ? w2 : w3;
    size_t dbase = ((size_t)(mat * NWG + wg) * 16) * Hh;
    size_t dlo   = ((size_t)(((mat >> 1) & 1) * NWG + wg) * 16) * Hh;
    const bool want_lo = use_lo && ((mat & 1) == 0);
    for (int it = 0; it < 64; ++it) {
        int idx = it * 256 + (int)threadIdx.x;
        int col = idx >> 10, k = idx & 1023;
        int cg = (col >> 2) * Hh + wg * 4 + (col & 3);
        float w = W[(size_t)k * 4096 + cg];
        unsigned short hi = f2bf(w);
        wh[dbase + (size_t)col * Hh + k] = hi;
        if (want_lo) wl[dlo + (size_t)col * Hh + k] = f2bf(w - bf2f(hi));
    }
}

template <bool USE_LO>
__global__ __launch_bounds__(512, 2) void k_lstm(
    const unsigned short* __restrict__ xTh,
    const unsigned short* __restrict__ xTl,
    const unsigned short* __restrict__ warrh,
    const unsigned short* __restrict__ warrl,
    unsigned int* __restrict__ hp0,        // [2][32][1024] u32 packed hi|lo<<16
    unsigned int* __restrict__ hp1,        // [2][32][1024] u32
    unsigned int* __restrict__ flags,      // [256] lines (arrivals) + go line
    unsigned int* __restrict__ ectr,       // [8] election ctr lines
    unsigned int* __restrict__ dflags,     // [8][32] lines (stage-done flags)
    unsigned short* __restrict__ hstage,   // [2][8][4][32][1024] bf16
    const float* __restrict__ b0,
    const float* __restrict__ b1,
    float* __restrict__ out)
{
    __shared__ float red[2][8][32][17];     // [layer][wave][batch(row)][col(+pad)]
    __shared__ int sRank;

    const int tid  = threadIdx.x;
    const int wave = tid >> 6;              // 0..7
    const int l    = tid & 63;
    const int wg   = blockIdx.x;
    unsigned int* go = flags + 8192;        // byte offset 32768

    // ---- XCD identification + rank election (one-time RMW) ----
    unsigned xraw;
    asm volatile("s_getreg_b32 %0, hwreg(20, 0, 32)" : "=s"(xraw));  // HW_REG_XCC_ID [m09]
    const int xcd = (int)(xraw & 7u);
    if (tid == 0) sRank = (int)atomicAdd(&ectr[(size_t)xcd * 32], 1u);
    __syncthreads();
    const int rank = sRank;

    // ---- persistent B fragments: K-slice of 128 per wave -> 4 kk frags ----
    i32x4 Bih0h[4], Bhh0h[4], Bih1h[4], Bhh1h[4];
    i32x4 Bih0l[4], Bih1l[4];
    {
        const size_t matStride = (size_t)NWG * 16 * Hh;
        const size_t wgOff = (size_t)wg * 16 * Hh;
        const int laneOff = (l & 15) * Hh + ((l >> 4) * 8);
        #pragma unroll
        for (int kk = 0; kk < 4; ++kk) {
            int off = laneOff + wave * 128 + kk * 32;
            Bih0h[kk] = pload_x4(warrh + 0 * matStride + wgOff + off);
            Bhh0h[kk] = pload_x4(warrh + 1 * matStride + wgOff + off);
            Bih1h[kk] = pload_x4(warrh + 2 * matStride + wgOff + off);
            Bhh1h[kk] = pload_x4(warrh + 3 * matStride + wgOff + off);
            if (USE_LO) {
                Bih0l[kk] = pload_x4(warrl + 0 * matStride + wgOff + off);
                Bih1l[kk] = pload_x4(warrl + 1 * matStride + wgOff + off);
            }
        }
        #pragma unroll
        for (int kk = 0; kk < 4; ++kk) {     // opacity: no remat
            asm volatile("" : "+v"(Bih0h[kk]), "+v"(Bhh0h[kk]),
                             "+v"(Bih1h[kk]), "+v"(Bhh1h[kk]));
            if (USE_LO)
                asm volatile("" : "+v"(Bih0l[kk]), "+v"(Bih1l[kk]));
        }
    }

    // ---- epilogue cell ownership (tid<256): <128 layer0, else layer1 ----
    const int cid = tid & 127;
    const int cb  = cid & 31;
    const int ca  = (cid >> 5) & 3;
    const int cu  = wg * 4 + ca;
    const float* bias = (tid < 128) ? b0 : b1;
    const float bi  = bias[cu];
    const float bf_ = bias[Hh + cu];
    const float bg  = bias[2 * Hh + cu];
    const float bo  = bias[3 * Hh + cu];
    float c = 0.f;

    const int laneA = (l & 15) * Hh + ((l >> 4) * 8);

    f32x4 a00, a01, a10, a11;

    // x-projection terms (layer 0, h-independent) for step sidx
    auto xterms = [&](int sidx, f32x4& A0, f32x4& A1) {
        const unsigned short* xh = xTh + (size_t)sidx * (Bb * Hh);
        const unsigned short* xl = xTl + (size_t)sidx * (Bb * Hh);
        #pragma unroll
        for (int m = 0; m < 2; ++m) {
            f32x4& A = m ? A1 : A0;
            #pragma unroll
            for (int kk = 0; kk < 4; ++kk) {
                const int off = laneA + m * 16 * Hh + wave * 128 + kk * 32;
                i32x4 axh = pload_x4(xh + off);
                mfma_bf16(A, axh, Bih0h[kk]);
                if (USE_LO) {
                    i32x4 axl = pload_x4(xl + off);
                    mfma_bf16(A, axh, Bih0l[kk]);
                    mfma_bf16(A, axl, Bih0h[kk]);
                }
            }
        }
    };

    a00 = f32x4{0,0,0,0}; a01 = f32x4{0,0,0,0};
    xterms(0, a00, a01);

    unsigned nx = 0, nx32 = 0;  // wgs on this XCD; read lazily after barrier 1

    for (int s = 0; s <= Tt; ++s) {
        const int par_w = s & 1;
        const int par_r = par_w ^ 1;
        const size_t parWOff32 = (size_t)par_w * (Bb * Hh);
        const size_t parROff32 = (size_t)par_r * (Bb * Hh);
        const unsigned short* stb = hstage + ((size_t)(s & 1) * 8 + xcd) * ST4E;

        a10 = f32x4{0,0,0,0}; a11 = f32x4{0,0,0,0};

        // ---- h-dependent MFMA terms from staged local-L2 copy ----
        #pragma unroll
        for (int m = 0; m < 2; ++m) {
            f32x4& acc0 = m ? a01 : a00;
            f32x4& acc1 = m ? a11 : a10;
            i32x4 g0h[4], g1h[4], g0l[4], g1l[4];
            #pragma unroll
            for (int kk = 0; kk < 4; ++kk) {
                const int off = laneA + m * 16 * Hh + wave * 128 + kk * 32;
                g0h[kk] = pload_x4(stb + off);                 // h0 hi
                g1h[kk] = pload_x4(stb + 2 * PLE + off);       // h1 hi
                if (USE_LO) {
                    g0l[kk] = pload_x4(stb + PLE + off);       // h0 lo
                    g1l[kk] = pload_x4(stb + 3 * PLE + off);   // h1 lo
                }
            }
            #pragma unroll
            for (int kk = 0; kk < 4; ++kk) {
                mfma_bf16(acc0, g0h[kk], Bhh0h[kk]);   // h0 * Whh0
                mfma_bf16(acc1, g0h[kk], Bih1h[kk]);   // y0 * Wih1
                mfma_bf16(acc1, g1h[kk], Bhh1h[kk]);   // h1 * Whh1
                if (USE_LO) {
                    mfma_bf16(acc0, g0l[kk], Bhh0h[kk]);   // dh0 * Whh0
                    mfma_bf16(acc1, g0h[kk], Bih1l[kk]);   // y0 * dWih1
                    mfma_bf16(acc1, g0l[kk], Bih1h[kk]);   // dy0 * Wih1
                    mfma_bf16(acc1, g1l[kk], Bhh1h[kk]);   // dh1 * Whh1
                }
            }
        }
        asm("s_nop 7\n\ts_nop 7" : "+v"(a00), "+v"(a01), "+v"(a10), "+v"(a11));

        {
            const int r0 = (l >> 4) * 4;   // C/D: col=lane&15, row=(lane>>4)*4+reg [m89]
            const int cc = l & 15;
            #pragma unroll
            for (int r = 0; r < 4; ++r) {
                red[0][wave][r0 + r][cc]      = a00[r];
                red[0][wave][16 + r0 + r][cc] = a01[r];
                red[1][wave][r0 + r][cc]      = a10[r];
                red[1][wave][16 + r0 + r][cc] = a11[r];
            }
        }
        __syncthreads();

        if (tid < 128) {                    // ---- layer 0 epilogue, t = s ----
            if (s < Tt) {
                float vi = bi, vf = bf_, vg = bg, vo = bo;
                #pragma unroll
                for (int w = 0; w < 8; ++w) {
                    vi += red[0][w][cb][ca];
                    vf += red[0][w][cb][4 + ca];
                    vg += red[0][w][cb][8 + ca];
                    vo += red[0][w][cb][12 + ca];
                }
                float ig = sigm(vi), fg = sigm(vf), gg = tanh_f(vg), og = sigm(vo);
                c = fg * c + ig * gg;
                float h = og * tanh_f(c);
                unsigned short hh = f2bf(h);
                unsigned short hl = f2bf(h - bf2f(hh));
                astore_u32(hp0 + parWOff32 + (size_t)cb * Hh + cu,
                           (unsigned)hh | ((unsigned)hl << 16));
                if (s == Tt - 1) {
                    out[16777216 + cb * Hh + cu] = h;          // h_n[0]
                    out[16777216 + 65536 + cb * Hh + cu] = c;  // c_n[0]
                }
            }
        } else if (tid < 256) {             // ---- layer 1 epilogue, t = s-1 ----
            if (s >= 1) {
                const int t = s - 1;
                float vi = bi, vf = bf_, vg = bg, vo = bo;
                #pragma unroll
                for (int w = 0; w < 8; ++w) {
                    vi += red[1][w][cb][ca];
                    vf += red[1][w][cb][4 + ca];
                    vg += red[1][w][cb][8 + ca];
                    vo += red[1][w][cb][12 + ca];
                }
                float ig = sigm(vi), fg = sigm(vf), gg = tanh_f(vg), og = sigm(vo);
                c = fg * c + ig * gg;
                float h = og * tanh_f(c);
                unsigned short hh = f2bf(h);
                unsigned short hl = f2bf(h - bf2f(hh));
                astore_u32(hp1 + parROff32 + (size_t)cb * Hh + cu,
                           (unsigned)hh | ((unsigned)hl << 16));
                out[(size_t)cb * (Tt * Hh) + (size_t)t * Hh + cu] = h;   // y1
                if (s == Tt) {
                    out[16777216 + 32768 + cb * Hh + cu] = h;            // h_n[1]
                    out[16777216 + 65536 + 32768 + cb * Hh + cu] = c;    // c_n[1]
                }
            }
        }

        // ---- hierarchical barrier + overlap(x-terms s+1) + per-XCD stage ----
        if (s < Tt) {
            const unsigned tgt = (unsigned)(s + 1);
            asm volatile("s_waitcnt vmcnt(0)" ::: "memory");  // drain packed h stores
            __syncthreads();
            if (tid == 0) astore_u32(flags + (size_t)wg * 32, tgt);  // arrival

            // overlap: next step's x-projection MFMAs (no h dependency)
            a00 = f32x4{0,0,0,0}; a01 = f32x4{0,0,0,0};
            xterms(s + 1, a00, a01);

            // hierarchical arrival detect: wg0 aggregates -> go word
            if (wg == 0) {
                int ok = 0;
                do {
                    unsigned f = (tid < 256) ? aload_u32(flags + (size_t)tid * 32) : tgt;
                    ok = __syncthreads_and((int)(f >= tgt));
                    if (!ok) __builtin_amdgcn_s_sleep(2);
                } while (!ok);
                if (tid == 0) astore_u32(go, tgt);
            } else {
                if (tid == 0) {
                    while (aload_u32(go) < tgt)
                        __builtin_amdgcn_s_sleep(4);
                }
                __syncthreads();
            }

            if (nx == 0) {                   // lazy: all elections done by now
                nx = aload_u32(ectr + (size_t)xcd * 32);
                nx32 = nx < 32u ? nx : 32u;
            }

            // stage slices: slice r -> packed buffer (r>>4), 8KB chunk (r&15).
            // Each thread: 1 aload_x4 (4 packed u32) -> unpack -> 2x8B writes.
            unsigned short* dstb = hstage + ((size_t)((s + 1) & 1) * 8 + xcd) * ST4E;
            for (int r = rank; r < 32; r += (int)nx) {
                const int buf = r >> 4;
                const unsigned int* sp = (buf == 0) ? (hp0 + parWOff32)
                                                    : (hp1 + parROff32);
                const int e = (r & 15) * 2048 + tid * 4;      // u32 elem index
                i32x4 v = aload_x4(sp + e);
                ushort4 hi4, lo4;
                hi4.x = (unsigned short)((unsigned)v[0] & 0xffffu);
                lo4.x = (unsigned short)((unsigned)v[0] >> 16);
                hi4.y = (unsigned short)((unsigned)v[1] & 0xffffu);
                lo4.y = (unsigned short)((unsigned)v[1] >> 16);
                hi4.z = (unsigned short)((unsigned)v[2] & 0xffffu);
                lo4.z = (unsigned short)((unsigned)v[2] >> 16);
                hi4.w = (unsigned short)((unsigned)v[3] & 0xffffu);
                lo4.w = (unsigned short)((unsigned)v[3] >> 16);
                unsigned short* dh = dstb + (buf == 0 ? 0 : 2 * PLE) + e;
                unsigned short* dl = dstb + (buf == 0 ? PLE : 3 * PLE) + e;
                *(ushort4*)dh = hi4;                           // local L2
                *(ushort4*)dl = lo4;
            }
            asm volatile("s_waitcnt vmcnt(0)" ::: "memory");  // staged stores L2-ack'd
            __syncthreads();                                  // all threads drained
            if (tid == 0 && rank < 32)                        // stage-done flag
                astore_u32(dflags + ((size_t)xcd * 32 + rank) * 32, tgt);
            // wait for this XCD's nx32 stagers
            int ok2 = 0;
            do {
                unsigned f = (tid < (int)nx32)
                    ? aload_u32(dflags + ((size_t)xcd * 32 + tid) * 32) : tgt;
                ok2 = __syncthreads_and((int)(f >= tgt));
                if (!ok2) __builtin_amdgcn_s_sleep(2);
            } while (!ok2);
        }
    }
}

extern "C" void kernel_launch(void* const* d_in, const int* in_sizes, int n_in,
                              void* d_out, int out_size, void* d_ws, size_t ws_size,
                              hipStream_t stream) {
    const float* x     = (const float*)d_in[0];
    const float* w_ih0 = (const float*)d_in[1];
    const float* w_hh0 = (const float*)d_in[2];
    const float* b0    = (const float*)d_in[3];
    const float* w_ih1 = (const float*)d_in[4];
    const float* w_hh1 = (const float*)d_in[5];
    const float* b1    = (const float*)d_in[6];
    float* out = (float*)d_out;

    const size_t SZ_WARRH = 33554432;   // 4*256*16*1024*2
    const size_t SZ_WARRL = 16777216;   // 2*256*16*1024*2
    const size_t SZ_XT    = 33619968;   // 513*32*1024*2
    const size_t SZ_HP    = 262144;     // [2][32][1024] u32 packed, per buffer
    const size_t SZ_FLAGS = 33024;      // 256 lines x 128B + go line
    const size_t SZ_ECTR  = 1024;       // 8 lines x 128B
    const size_t SZ_DFLG  = 32768;      // 8*32 lines x 128B
    const size_t SZ_STAGE = 4194304;    // 2*8*4*32*1024*2B

    char* ws = (char*)d_ws;
    unsigned short* warrh = (unsigned short*)ws;
    unsigned short* warrl = (unsigned short*)(ws + SZ_WARRH);
    unsigned short* xTh   = (unsigned short*)(ws + SZ_WARRH + SZ_WARRL);
    unsigned short* xTl   = (unsigned short*)(ws + SZ_WARRH + SZ_WARRL + SZ_XT);
    char* zbase = ws + SZ_WARRH + SZ_WARRL + 2 * SZ_XT;
    unsigned int* hp0    = (unsigned int*)zbase;
    unsigned int* hp1    = (unsigned int*)(zbase + SZ_HP);
    unsigned int* flags  = (unsigned int*)(zbase + 2 * SZ_HP);
    unsigned int* ectr   = (unsigned int*)(zbase + 2 * SZ_HP + SZ_FLAGS);
    unsigned int* dflags = (unsigned int*)(zbase + 2 * SZ_HP + SZ_FLAGS + SZ_ECTR);
    unsigned short* hstage =
        (unsigned short*)(zbase + 2 * SZ_HP + SZ_FLAGS + SZ_ECTR + SZ_DFLG);

    const size_t ZSZ  = 2 * SZ_HP + SZ_FLAGS + SZ_ECTR + SZ_DFLG + SZ_STAGE;
    const size_t FULL = SZ_WARRH + SZ_WARRL + 2 * SZ_XT + ZSZ;
    const bool use_lo = ws_size >= FULL;

    hipMemsetAsync(zbase, 0, ZSZ, stream);   // h+flags+ectr+dflags+stage (replay-safe)
    hipLaunchKernelGGL(k_xT,   dim3(16416), dim3(256), 0, stream, x, xTh, xTl, (int)use_lo);
    hipLaunchKernelGGL(k_warr, dim3(1024),  dim3(256), 0, stream,
                       w_ih0, w_hh0, w_ih1, w_hh1, warrh, warrl, (int)use_lo);
    if (use_lo) {
        hipLaunchKernelGGL(k_lstm<true>, dim3(256), dim3(512), 0, stream,
                           xTh, xTl, warrh, warrl, hp0, hp1,
                           flags, ectr, dflags, hstage, b0, b1, out);
    } else {
        hipLaunchKernelGGL(k_lstm<false>, dim3(256), dim3(512), 0, stream,
                           xTh, xTl, warrh, warrl, hp0, hp1,
                           flags, ectr, dflags, hstage, b0, b1, out);
    }
}

// Round 13
// 7767.582 us; speedup vs baseline: 1.0611x; 1.0611x over previous
//
#include <hip/hip_runtime.h>
#include <hip/hip_bf16.h>

// ---------------------------------------------------------------------------
// 2-layer LSTM, B=32, T=512, H=1024, fp32 in/out.
// Round 13 (base = r11 symmetric-arrival, 7.87ms; r12 hierarchy reverted):
//   UC transaction-width fixes (bytes unchanged, counts 4-8x lower):
//   1. h writes: epilogue -> LDS hsh[2][32][4]; wave0's 64 threads gather
//      4 u32 each -> ONE global_store_dwordx4 sc0 sc1 (64 stores/wg/step
//      instead of 256 scattered 4B stores). buf1 not gathered at s==0
//      (keeps memset-zero initial h1).
//   2. stage reads: one global_load_dwordx4 sc0 sc1 per thread (was 2x8B
//      atomics). Safe asm: =&v early-clobber + internal s_waitcnt + data
//      dependence through the result (rule-18-proof).
//   Numerics/protocol otherwise byte-identical to r11 (passed, 0.0546875).
// ---------------------------------------------------------------------------

constexpr int Hh = 1024;
constexpr int Bb = 32;
constexpr int Tt = 512;
constexpr int NWG = 256;
constexpr int PLE  = 32 * 1024;        // elems per staged plane [32][1024]
constexpr int ST4E = 4 * PLE;          // 4 planes per staged slot

typedef float f32x4 __attribute__((ext_vector_type(4)));
typedef int   i32x4 __attribute__((ext_vector_type(4)));

__device__ inline void mfma_bf16(f32x4& acc, i32x4 a, i32x4 b) {
    // s_nop 2 guards compiler-inserted VALU writes before the MFMA reads.
    asm("s_nop 2\n\tv_mfma_f32_16x16x32_bf16 %0, %1, %2, %0"
        : "+v"(acc) : "v"(a), "v"(b));
}

// Coherent-point 16B load (stage phase): dwordx4 with internal waitcnt;
// =&v early-clobber so dest can't alias the address pair; consumers depend
// on the result -> ordering is data-enforced.
__device__ inline i32x4 uload_x4(const void* p) {
    i32x4 r;
    asm volatile("global_load_dwordx4 %0, %1, off sc0 sc1\n\ts_waitcnt vmcnt(0)"
                 : "=&v"(r) : "v"(p) : "memory");
    return r;
}
// Coherent-point 16B store (h publish). Drained by later s_waitcnt vmcnt(0).
__device__ inline void ustore_x4(void* p, i32x4 v) {
    asm volatile("global_store_dwordx4 %0, %1, off sc0 sc1"
                 :: "v"(p), "v"(v) : "memory");
}
__device__ inline i32x4 pload_x4(const unsigned short* p) {  // plain cached
    return *(const i32x4*)p;
}
__device__ inline void astore_u32(unsigned int* p, unsigned v) {
    __hip_atomic_store(p, v, __ATOMIC_RELAXED, __HIP_MEMORY_SCOPE_AGENT);
}
__device__ inline unsigned aload_u32(const unsigned int* p) {
    return __hip_atomic_load(p, __ATOMIC_RELAXED, __HIP_MEMORY_SCOPE_AGENT);
}

__device__ inline unsigned short f2bf(float f) {
    unsigned u = __float_as_uint(f);
    u += 0x7fffu + ((u >> 16) & 1u);   // round-to-nearest-even
    return (unsigned short)(u >> 16);
}
__device__ inline float bf2f(unsigned short s) {
    return __uint_as_float((unsigned)s << 16);
}

__device__ inline float sigm(float x)  { return 1.f / (1.f + __expf(-x)); }
__device__ inline float tanh_f(float x){ return 1.f - 2.f / (__expf(2.f * x) + 1.f); }

// x [32][512][1024] f32 -> xT hi/lo [513][32][1024] bf16 (slot 512 zeroed)
__global__ __launch_bounds__(256) void k_xT(const float* __restrict__ x,
                                            unsigned short* __restrict__ xh,
                                            unsigned short* __restrict__ xl,
                                            int use_lo) {
    int bid = blockIdx.x;               // 0..16415
    int t = bid >> 5, b = bid & 31;
    size_t o = ((size_t)t * Bb + b) * Hh;
    if (t == Tt) {
        ushort4 z = {0, 0, 0, 0};
        ((ushort4*)(xh + o))[threadIdx.x] = z;
        if (use_lo) ((ushort4*)(xl + o))[threadIdx.x] = z;
        return;
    }
    const float4* src = (const float4*)(x + ((size_t)b * Tt + t) * Hh);
    float4 v = src[threadIdx.x];
    ushort4 hi;
    hi.x = f2bf(v.x); hi.y = f2bf(v.y); hi.z = f2bf(v.z); hi.w = f2bf(v.w);
    ((ushort4*)(xh + o))[threadIdx.x] = hi;
    if (use_lo) {
        ushort4 lo;
        lo.x = f2bf(v.x - bf2f(hi.x));
        lo.y = f2bf(v.y - bf2f(hi.y));
        lo.z = f2bf(v.z - bf2f(hi.z));
        lo.w = f2bf(v.w - bf2f(hi.w));
        ((ushort4*)(xl + o))[threadIdx.x] = lo;
    }
}

// W[mat] [1024][4096] f32 -> wh[mat][wg][col(16)][k(1024)] bf16 (4 mats),
// lo planes only for mats 0,2 (w_ih0, w_ih1) packed at lo-slot mat>>1.
__global__ __launch_bounds__(256) void k_warr(const float* __restrict__ w0,
                                              const float* __restrict__ w1,
                                              const float* __restrict__ w2,
                                              const float* __restrict__ w3,
                                              unsigned short* __restrict__ wh,
                                              unsigned short* __restrict__ wl,
                                              int use_lo) {
    int bid = blockIdx.x;               // 0..1023
    int mat = bid >> 8, wg = bid & 255;
    const float* W = (mat == 0) ? w0 : (mat == 1) ? w1 : (mat == 2) ? w2 : w3;
    size_t dbase = ((size_t)(mat * NWG + wg) * 16) * Hh;
    size_t dlo   = ((size_t)(((mat >> 1) & 1) * NWG + wg) * 16) * Hh;
    const bool want_lo = use_lo && ((mat & 1) == 0);
    for (int it = 0; it < 64; ++it) {
        int idx = it * 256 + (int)threadIdx.x;
        int col = idx >> 10, k = idx & 1023;
        int cg = (col >> 2) * Hh + wg * 4 + (col & 3);
        float w = W[(size_t)k * 4096 + cg];
        unsigned short hi = f2bf(w);
        wh[dbase + (size_t)col * Hh + k] = hi;
        if (want_lo) wl[dlo + (size_t)col * Hh + k] = f2bf(w - bf2f(hi));
    }
}

template <bool USE_LO>
__global__ __launch_bounds__(512, 2) void k_lstm(
    const unsigned short* __restrict__ xTh,
    const unsigned short* __restrict__ xTl,
    const unsigned short* __restrict__ warrh,
    const unsigned short* __restrict__ warrl,
    unsigned int* __restrict__ hp0,        // [2][32][1024] u32 packed hi|lo<<16
    unsigned int* __restrict__ hp1,        // [2][32][1024] u32
    unsigned int* __restrict__ flags,      // [256] lines of 32 u32 (arrivals)
    unsigned int* __restrict__ ectr,       // [8] election ctr lines
    unsigned int* __restrict__ dflags,     // [8][32] lines (stage-done flags)
    unsigned short* __restrict__ hstage,   // [2][8][4][32][1024] bf16
    const float* __restrict__ b0,
    const float* __restrict__ b1,
    float* __restrict__ out)
{
    __shared__ float red[2][8][32][17];     // [layer][wave][batch(row)][col(+pad)]
    __shared__ unsigned hsh[2][32][4];      // packed h staging: [buf][cb][ca]
    __shared__ int sRank;

    const int tid  = threadIdx.x;
    const int wave = tid >> 6;              // 0..7
    const int l    = tid & 63;
    const int wg   = blockIdx.x;

    // ---- XCD identification + rank election (one-time RMW) ----
    unsigned xraw;
    asm volatile("s_getreg_b32 %0, hwreg(20, 0, 32)" : "=s"(xraw));  // HW_REG_XCC_ID [m09]
    const int xcd = (int)(xraw & 7u);
    if (tid == 0) sRank = (int)atomicAdd(&ectr[(size_t)xcd * 32], 1u);
    __syncthreads();
    const int rank = sRank;

    // ---- persistent B fragments: K-slice of 128 per wave -> 4 kk frags ----
    i32x4 Bih0h[4], Bhh0h[4], Bih1h[4], Bhh1h[4];
    i32x4 Bih0l[4], Bih1l[4];
    {
        const size_t matStride = (size_t)NWG * 16 * Hh;
        const size_t wgOff = (size_t)wg * 16 * Hh;
        const int laneOff = (l & 15) * Hh + ((l >> 4) * 8);
        #pragma unroll
        for (int kk = 0; kk < 4; ++kk) {
            int off = laneOff + wave * 128 + kk * 32;
            Bih0h[kk] = pload_x4(warrh + 0 * matStride + wgOff + off);
            Bhh0h[kk] = pload_x4(warrh + 1 * matStride + wgOff + off);
            Bih1h[kk] = pload_x4(warrh + 2 * matStride + wgOff + off);
            Bhh1h[kk] = pload_x4(warrh + 3 * matStride + wgOff + off);
            if (USE_LO) {
                Bih0l[kk] = pload_x4(warrl + 0 * matStride + wgOff + off);
                Bih1l[kk] = pload_x4(warrl + 1 * matStride + wgOff + off);
            }
        }
        #pragma unroll
        for (int kk = 0; kk < 4; ++kk) {     // opacity: no remat
            asm volatile("" : "+v"(Bih0h[kk]), "+v"(Bhh0h[kk]),
                             "+v"(Bih1h[kk]), "+v"(Bhh1h[kk]));
            if (USE_LO)
                asm volatile("" : "+v"(Bih0l[kk]), "+v"(Bih1l[kk]));
        }
    }

    // ---- epilogue cell ownership (tid<256): <128 layer0, else layer1 ----
    const int cid = tid & 127;
    const int cb  = cid & 31;
    const int ca  = (cid >> 5) & 3;
    const int cu  = wg * 4 + ca;
    const float* bias = (tid < 128) ? b0 : b1;
    const float bi  = bias[cu];
    const float bf_ = bias[Hh + cu];
    const float bg  = bias[2 * Hh + cu];
    const float bo  = bias[3 * Hh + cu];
    float c = 0.f;

    const int laneA = (l & 15) * Hh + ((l >> 4) * 8);

    f32x4 a00, a01, a10, a11;

    // x-projection terms (layer 0, h-independent) for step sidx
    auto xterms = [&](int sidx, f32x4& A0, f32x4& A1) {
        const unsigned short* xh = xTh + (size_t)sidx * (Bb * Hh);
        const unsigned short* xl = xTl + (size_t)sidx * (Bb * Hh);
        #pragma unroll
        for (int m = 0; m < 2; ++m) {
            f32x4& A = m ? A1 : A0;
            #pragma unroll
            for (int kk = 0; kk < 4; ++kk) {
                const int off = laneA + m * 16 * Hh + wave * 128 + kk * 32;
                i32x4 axh = pload_x4(xh + off);
                mfma_bf16(A, axh, Bih0h[kk]);
                if (USE_LO) {
                    i32x4 axl = pload_x4(xl + off);
                    mfma_bf16(A, axh, Bih0l[kk]);
                    mfma_bf16(A, axl, Bih0h[kk]);
                }
            }
        }
    };

    a00 = f32x4{0,0,0,0}; a01 = f32x4{0,0,0,0};
    xterms(0, a00, a01);

    unsigned nx = 0, nx32 = 0;  // wgs on this XCD; read lazily after barrier 1

    for (int s = 0; s <= Tt; ++s) {
        const int par_w = s & 1;
        const int par_r = par_w ^ 1;
        const size_t parWOff32 = (size_t)par_w * (Bb * Hh);
        const size_t parROff32 = (size_t)par_r * (Bb * Hh);
        const unsigned short* stb = hstage + ((size_t)(s & 1) * 8 + xcd) * ST4E;

        a10 = f32x4{0,0,0,0}; a11 = f32x4{0,0,0,0};

        // ---- h-dependent MFMA terms from staged local-L2 copy ----
        #pragma unroll
        for (int m = 0; m < 2; ++m) {
            f32x4& acc0 = m ? a01 : a00;
            f32x4& acc1 = m ? a11 : a10;
            i32x4 g0h[4], g1h[4], g0l[4], g1l[4];
            #pragma unroll
            for (int kk = 0; kk < 4; ++kk) {
                const int off = laneA + m * 16 * Hh + wave * 128 + kk * 32;
                g0h[kk] = pload_x4(stb + off);                 // h0 hi
                g1h[kk] = pload_x4(stb + 2 * PLE + off);       // h1 hi
                if (USE_LO) {
                    g0l[kk] = pload_x4(stb + PLE + off);       // h0 lo
                    g1l[kk] = pload_x4(stb + 3 * PLE + off);   // h1 lo
                }
            }
            #pragma unroll
            for (int kk = 0; kk < 4; ++kk) {
                mfma_bf16(acc0, g0h[kk], Bhh0h[kk]);   // h0 * Whh0
                mfma_bf16(acc1, g0h[kk], Bih1h[kk]);   // y0 * Wih1
                mfma_bf16(acc1, g1h[kk], Bhh1h[kk]);   // h1 * Whh1
                if (USE_LO) {
                    mfma_bf16(acc0, g0l[kk], Bhh0h[kk]);   // dh0 * Whh0
                    mfma_bf16(acc1, g0h[kk], Bih1l[kk]);   // y0 * dWih1
                    mfma_bf16(acc1, g0l[kk], Bih1h[kk]);   // dy0 * Wih1
                    mfma_bf16(acc1, g1l[kk], Bhh1h[kk]);   // dh1 * Whh1
                }
            }
        }
        asm("s_nop 7\n\ts_nop 7" : "+v"(a00), "+v"(a01), "+v"(a10), "+v"(a11));

        {
            const int r0 = (l >> 4) * 4;   // C/D: col=lane&15, row=(lane>>4)*4+reg [m89]
            const int cc = l & 15;
            #pragma unroll
            for (int r = 0; r < 4; ++r) {
                red[0][wave][r0 + r][cc]      = a00[r];
                red[0][wave][16 + r0 + r][cc] = a01[r];
                red[1][wave][r0 + r][cc]      = a10[r];
                red[1][wave][16 + r0 + r][cc] = a11[r];
            }
        }
        __syncthreads();

        if (tid < 128) {                    // ---- layer 0 epilogue, t = s ----
            if (s < Tt) {
                float vi = bi, vf = bf_, vg = bg, vo = bo;
                #pragma unroll
                for (int w = 0; w < 8; ++w) {
                    vi += red[0][w][cb][ca];
                    vf += red[0][w][cb][4 + ca];
                    vg += red[0][w][cb][8 + ca];
                    vo += red[0][w][cb][12 + ca];
                }
                float ig = sigm(vi), fg = sigm(vf), gg = tanh_f(vg), og = sigm(vo);
                c = fg * c + ig * gg;
                float h = og * tanh_f(c);
                unsigned short hh = f2bf(h);
                unsigned short hl = f2bf(h - bf2f(hh));
                hsh[0][cb][ca] = (unsigned)hh | ((unsigned)hl << 16);
                if (s == Tt - 1) {
                    out[16777216 + cb * Hh + cu] = h;          // h_n[0]
                    out[16777216 + 65536 + cb * Hh + cu] = c;  // c_n[0]
                }
            }
        } else if (tid < 256) {             // ---- layer 1 epilogue, t = s-1 ----
            if (s >= 1) {
                const int t = s - 1;
                float vi = bi, vf = bf_, vg = bg, vo = bo;
                #pragma unroll
                for (int w = 0; w < 8; ++w) {
                    vi += red[1][w][cb][ca];
                    vf += red[1][w][cb][4 + ca];
                    vg += red[1][w][cb][8 + ca];
                    vo += red[1][w][cb][12 + ca];
                }
                float ig = sigm(vi), fg = sigm(vf), gg = tanh_f(vg), og = sigm(vo);
                c = fg * c + ig * gg;
                float h = og * tanh_f(c);
                unsigned short hh = f2bf(h);
                unsigned short hl = f2bf(h - bf2f(hh));
                hsh[1][cb][ca] = (unsigned)hh | ((unsigned)hl << 16);
                out[(size_t)cb * (Tt * Hh) + (size_t)t * Hh + cu] = h;   // y1
                if (s == Tt) {
                    out[16777216 + 32768 + cb * Hh + cu] = h;            // h_n[1]
                    out[16777216 + 65536 + 32768 + cb * Hh + cu] = c;    // c_n[1]
                }
            }
        }

        // ---- publish h (16B UC stores) + barrier + overlap + stage ----
        if (s < Tt) {
            const unsigned tgt = (unsigned)(s + 1);
            __syncthreads();                 // hsh (LDS) visible to wave 0
            if (tid < 64) {                  // wave 0: gather + 16B UC stores
                const int buf = tid >> 5;    // 0: h0 (slot par_w), 1: h1 (slot par_r)
                const int cbb = tid & 31;
                if (buf == 0 || s >= 1) {    // h1 not produced at s==0 (keep zeros)
                    i32x4 hv;
                    hv[0] = (int)hsh[buf][cbb][0];
                    hv[1] = (int)hsh[buf][cbb][1];
                    hv[2] = (int)hsh[buf][cbb][2];
                    hv[3] = (int)hsh[buf][cbb][3];
                    unsigned int* dst = (buf ? (hp1 + parROff32) : (hp0 + parWOff32))
                                        + (size_t)cbb * Hh + wg * 4;
                    ustore_x4(dst, hv);
                }
            }
            asm volatile("s_waitcnt vmcnt(0)" ::: "memory");  // wave0 drains h stores
            __syncthreads();
            if (tid == 0) astore_u32(flags + (size_t)wg * 32, tgt);  // arrival

            // overlap: next step's x-projection MFMAs (no h dependency)
            a00 = f32x4{0,0,0,0}; a01 = f32x4{0,0,0,0};
            xterms(s + 1, a00, a01);

            // symmetric arrival detect (r11-proven; tid<256 poll one wg each)
            int ok = 0;
            do {
                unsigned f = (tid < 256) ? aload_u32(flags + (size_t)tid * 32) : tgt;
                ok = __syncthreads_and((int)(f >= tgt));
                if (!ok) __builtin_amdgcn_s_sleep(2);
            } while (!ok);

            if (nx == 0) {                   // lazy: all elections done by now
                nx = aload_u32(ectr + (size_t)xcd * 32);
                nx32 = nx < 32u ? nx : 32u;
            }

            // stage slices: slice r -> packed buffer (r>>4), 8KB chunk (r&15).
            // Each thread: ONE 16B UC load -> unpack -> 2x8B local-L2 writes.
            unsigned short* dstb = hstage + ((size_t)((s + 1) & 1) * 8 + xcd) * ST4E;
            for (int r = rank; r < 32; r += (int)nx) {
                const int buf = r >> 4;
                const unsigned int* sp = (buf == 0) ? (hp0 + parWOff32)
                                                    : (hp1 + parROff32);
                const int e = (r & 15) * 2048 + tid * 4;      // u32 elem index
                i32x4 v = uload_x4(sp + e);
                ushort4 hi4, lo4;
                hi4.x = (unsigned short)((unsigned)v[0] & 0xffffu);
                lo4.x = (unsigned short)((unsigned)v[0] >> 16);
                hi4.y = (unsigned short)((unsigned)v[1] & 0xffffu);
                lo4.y = (unsigned short)((unsigned)v[1] >> 16);
                hi4.z = (unsigned short)((unsigned)v[2] & 0xffffu);
                lo4.z = (unsigned short)((unsigned)v[2] >> 16);
                hi4.w = (unsigned short)((unsigned)v[3] & 0xffffu);
                lo4.w = (unsigned short)((unsigned)v[3] >> 16);
                unsigned short* dh = dstb + (buf == 0 ? 0 : 2 * PLE) + e;
                unsigned short* dl = dstb + (buf == 0 ? PLE : 3 * PLE) + e;
                *(ushort4*)dh = hi4;                           // local L2
                *(ushort4*)dl = lo4;
            }
            asm volatile("s_waitcnt vmcnt(0)" ::: "memory");  // staged stores L2-ack'd
            __syncthreads();                                  // all threads drained
            if (tid == 0 && rank < 32)                        // stage-done flag
                astore_u32(dflags + ((size_t)xcd * 32 + rank) * 32, tgt);
            // wait for this XCD's nx32 stagers
            int ok2 = 0;
            do {
                unsigned f = (tid < (int)nx32)
                    ? aload_u32(dflags + ((size_t)xcd * 32 + tid) * 32) : tgt;
                ok2 = __syncthreads_and((int)(f >= tgt));
                if (!ok2) __builtin_amdgcn_s_sleep(2);
            } while (!ok2);
        }
    }
}

extern "C" void kernel_launch(void* const* d_in, const int* in_sizes, int n_in,
                              void* d_out, int out_size, void* d_ws, size_t ws_size,
                              hipStream_t stream) {
    const float* x     = (const float*)d_in[0];
    const float* w_ih0 = (const float*)d_in[1];
    const float* w_hh0 = (const float*)d_in[2];
    const float* b0    = (const float*)d_in[3];
    const float* w_ih1 = (const float*)d_in[4];
    const float* w_hh1 = (const float*)d_in[5];
    const float* b1    = (const float*)d_in[6];
    float* out = (float*)d_out;

    const size_t SZ_WARRH = 33554432;   // 4*256*16*1024*2
    const size_t SZ_WARRL = 16777216;   // 2*256*16*1024*2
    const size_t SZ_XT    = 33619968;   // 513*32*1024*2
    const size_t SZ_HP    = 262144;     // [2][32][1024] u32 packed, per buffer
    const size_t SZ_FLAGS = 32768;      // 256 lines x 128B
    const size_t SZ_ECTR  = 1024;       // 8 lines x 128B
    const size_t SZ_DFLG  = 32768;      // 8*32 lines x 128B
    const size_t SZ_STAGE = 4194304;    // 2*8*4*32*1024*2B

    char* ws = (char*)d_ws;
    unsigned short* warrh = (unsigned short*)ws;
    unsigned short* warrl = (unsigned short*)(ws + SZ_WARRH);
    unsigned short* xTh   = (unsigned short*)(ws + SZ_WARRH + SZ_WARRL);
    unsigned short* xTl   = (unsigned short*)(ws + SZ_WARRH + SZ_WARRL + SZ_XT);
    char* zbase = ws + SZ_WARRH + SZ_WARRL + 2 * SZ_XT;
    unsigned int* hp0    = (unsigned int*)zbase;
    unsigned int* hp1    = (unsigned int*)(zbase + SZ_HP);
    unsigned int* flags  = (unsigned int*)(zbase + 2 * SZ_HP);
    unsigned int* ectr   = (unsigned int*)(zbase + 2 * SZ_HP + SZ_FLAGS);
    unsigned int* dflags = (unsigned int*)(zbase + 2 * SZ_HP + SZ_FLAGS + SZ_ECTR);
    unsigned short* hstage =
        (unsigned short*)(zbase + 2 * SZ_HP + SZ_FLAGS + SZ_ECTR + SZ_DFLG);

    const size_t ZSZ  = 2 * SZ_HP + SZ_FLAGS + SZ_ECTR + SZ_DFLG + SZ_STAGE;
    const size_t FULL = SZ_WARRH + SZ_WARRL + 2 * SZ_XT + ZSZ;
    const bool use_lo = ws_size >= FULL;

    hipMemsetAsync(zbase, 0, ZSZ, stream);   // h+flags+ectr+dflags+stage (replay-safe)
    hipLaunchKernelGGL(k_xT,   dim3(16416), dim3(256), 0, stream, x, xTh, xTl, (int)use_lo);
    hipLaunchKernelGGL(k_warr, dim3(1024),  dim3(256), 0, stream,
                       w_ih0, w_hh0, w_ih1, w_hh1, warrh, warrl, (int)use_lo);
    if (use_lo) {
        hipLaunchKernelGGL(k_lstm<true>, dim3(256), dim3(512), 0, stream,
                           xTh, xTl, warrh, warrl, hp0, hp1,
                           flags, ectr, dflags, hstage, b0, b1, out);
    } else {
        hipLaunchKernelGGL(k_lstm<false>, dim3(256), dim3(512), 0, stream,
                           xTh, xTl, warrh, warrl, hp0, hp1,
                           flags, ectr, dflags, hstage, b0, b1, out);
    }
}